// Round 7
// baseline (108.764 us; speedup 1.0000x reference)
//
#include <hip/hip_runtime.h>
#include <hip/hip_cooperative_groups.h>

namespace cg = cooperative_groups;

#define NPOS 1024
#define NBATCH 64
#define DROW 2050
#define NPG 18                    // chunk-pair groups per batch (2 cps each, 36 total)
#define NBLK (NBATCH * NPG)       // 1152 blocks

// Single cooperative dispatch.
// Per block: rebuild the batch's 1024 pre-scaled positions in LDS (shuffle
// block-scan; P = {X,Y,Z,-|p|^2}, ALPHA = sqrt(4*log2 e) so
// exp(-4 d2) = exp2(2 p.q + p.w + q.w)). Then process two triangular
// 128x128 chunk-pairs: 36 cps = 8 diagonal (weight 1, includes i==j diag,
// subtracted as exact constant) + 28 upper pairs (weight 2, symmetry).
// Thread layout per cp: R=2 register i's (il, il+64), wave w sweeps j-quarter
// w*32..+32 via broadcast ds_read_b128. Block partial -> part[]; grid.sync();
// block 0 reduces 1152 partials and writes the scalar.
__global__ __launch_bounds__(256) void fused_kernel(const float* __restrict__ conf,
                                                    float* __restrict__ part,
                                                    float* __restrict__ out) {
  __shared__ float4 P[NPOS];   // 16 KB
  __shared__ float wsx[4], wsy[4], wsz[4];
  __shared__ float red[4];

  const int g = blockIdx.x % NPG;
  const int b = blockIdx.x / NPG;
  const int tid = threadIdx.x;
  const int lane = tid & 63, w = tid >> 6;
  const float* __restrict__ row = conf + b * DROW;
  const float ALPHA = 2.40224481f;  // sqrt(5.770780163555856)

  // ---- phase 1: chain scan -> LDS positions ----
  float lx[4], ly[4], lz[4];
  float rx = 0.f, ry = 0.f, rz = 0.f;
#pragma unroll
  for (int k = 0; k < 4; ++k) {
    const int n = 4 * tid + k;
    if (n > 0) {
      const float2 rr = *reinterpret_cast<const float2*>(row + 2 + 2 * n);
      const float r1 = rr.x + 0.5f;
      const float r2 = rr.y + 0.5f;
      const float ct = 1.f - 2.f * r2;                    // cos(theta)
      const float st = sqrtf(fmaxf(0.f, 1.f - ct * ct));  // sin(theta)
      const float sp = __builtin_amdgcn_sinf(r1);         // sin(2*pi*r1)
      const float cp = __builtin_amdgcn_cosf(r1);
      rx += st * cp; ry += st * sp; rz += ct;
    }
    lx[k] = rx; ly[k] = ry; lz[k] = rz;
  }
  const float ttx = rx, tty = ry, ttz = rz;
  float sx = rx, sy = ry, sz = rz;
#pragma unroll
  for (int off = 1; off < 64; off <<= 1) {
    const float ax = __shfl_up(sx, off, 64);
    const float ay = __shfl_up(sy, off, 64);
    const float az = __shfl_up(sz, off, 64);
    if (lane >= off) { sx += ax; sy += ay; sz += az; }
  }
  if (lane == 63) { wsx[w] = sx; wsy[w] = sy; wsz[w] = sz; }
  __syncthreads();
  float cx = 0.f, cy = 0.f, cz = 0.f;
#pragma unroll
  for (int ww = 0; ww < 3; ++ww)
    if (ww < w) { cx += wsx[ww]; cy += wsy[ww]; cz += wsz[ww]; }

  const float ox = row[1] + cx + (sx - ttx);  // init + exclusive prefix
  const float oy = row[2] + cy + (sy - tty);
  const float oz = row[3] + cz + (sz - ttz);
#pragma unroll
  for (int k = 0; k < 4; ++k) {
    const float X = ALPHA * (ox + lx[k]);
    const float Y = ALPHA * (oy + ly[k]);
    const float Z = ALPHA * (oz + lz[k]);
    float n2 = X * X; n2 = fmaf(Y, Y, n2); n2 = fmaf(Z, Z, n2);
    P[4 * tid + k] = make_float4(X, Y, Z, -n2);
  }
  __syncthreads();

  // ---- phase 2: two triangular chunk-pairs, R=2 x j-quarter ----
  const int il = tid & 63;   // i lane within chunk (covers il and il+64)
  const int jq = w;          // wave id = j-quarter (wave-uniform)
  float total = 0.f;
#pragma unroll
  for (int s = 0; s < 2; ++s) {
    const int p = 2 * g + s;
    int ci, cj;
    float wgt;
    if (p < 8) {
      ci = p; cj = p; wgt = 1.f;
    } else {
      int r = p - 8;
      ci = 0;
      while (r >= 7 - ci) { r -= 7 - ci; ++ci; }
      cj = ci + 1 + r; wgt = 2.f;
    }
    const float4 A = P[ci * 128 + il];
    const float4 B = P[ci * 128 + il + 64];
    const float dAx = 2.f * A.x, dAy = 2.f * A.y, dAz = 2.f * A.z;
    const float dBx = 2.f * B.x, dBy = 2.f * B.y, dBz = 2.f * B.z;
    const float4* __restrict__ Q = &P[cj * 128 + jq * 32];
    float a0 = 0.f, a1 = 0.f;
#pragma unroll 4
    for (int jj = 0; jj < 32; ++jj) {
      const float4 q = Q[jj];  // wave-uniform -> broadcast
      const float gA = fmaf(dAx, q.x, fmaf(dAy, q.y, fmaf(dAz, q.z, A.w + q.w)));
      const float gB = fmaf(dBx, q.x, fmaf(dBy, q.y, fmaf(dBz, q.z, B.w + q.w)));
      a0 += __builtin_amdgcn_exp2f(gA);
      a1 += __builtin_amdgcn_exp2f(gB);
    }
    total = fmaf(wgt, a0 + a1, total);
  }

  // ---- block reduce -> part[bx] ----
#pragma unroll
  for (int off = 32; off; off >>= 1) total += __shfl_down(total, off, 64);
  if (lane == 0) red[w] = total;
  __syncthreads();
  if (tid == 0) {
    part[blockIdx.x] = (red[0] + red[1]) + (red[2] + red[3]);
    __threadfence();  // device-scope release before grid barrier
  }

  // ---- grid-wide barrier, block 0 finalizes ----
  cg::this_grid().sync();
  if (blockIdx.x == 0) {
    float sacc = 0.f;
    for (int i = tid; i < NBLK; i += 256) sacc += part[i];
#pragma unroll
    for (int off = 32; off; off >>= 1) sacc += __shfl_down(sacc, off, 64);
    if (lane == 0) red[w] = sacc;
    __syncthreads();
    if (tid == 0) {
      // SIGMA * sum - SIGMA * NPOS * NBATCH (diagonal of diag chunks)
      out[0] = 10.0f * ((red[0] + red[1]) + (red[2] + red[3])) - 655360.0f;
    }
  }
}

extern "C" void kernel_launch(void* const* d_in, const int* in_sizes, int n_in,
                              void* d_out, int out_size, void* d_ws, size_t ws_size,
                              hipStream_t stream) {
  const float* conf = (const float*)d_in[0];
  float* out = (float*)d_out;
  float* part = (float*)d_ws;  // NBLK floats
  void* args[] = {(void*)&conf, (void*)&part, (void*)&out};
  hipLaunchCooperativeKernel((const void*)fused_kernel, dim3(NBLK), dim3(256),
                             args, 0, stream);
}

// Round 8
// 19.128 us; speedup vs baseline: 5.6860x; 5.6860x over previous
//
#include <hip/hip_runtime.h>

#define NPOS 1024
#define NBATCH 64
#define DROW 2050
#define NPG 18                    // chunk-pair groups per batch (2 cps each, 36 total)
#define NBLK (NBATCH * NPG)       // 1152 blocks

// Two dispatches: fused_kernel (scan + triangular pair sweep -> per-block
// partial, NO atomics, NO grid sync) then a 1-block reduce.
// Per block: rebuild the batch's 1024 pre-scaled positions in LDS (shuffle
// block-scan; P = {X,Y,Z,-|p|^2}, ALPHA = sqrt(4*log2 e) so
// exp(-4 d2) = exp2(2 p.q + p.w + q.w)). Then two triangular 128x128
// chunk-pairs: 36 cps = 8 diagonal (weight 1; i==j diagonal subtracted as the
// exact constant downstream) + 28 upper pairs (weight 2, symmetry).
// Per cp: R=2 register i's (il, il+64), wave w sweeps j-quarter w*32..+32 via
// broadcast ds_read_b128.
__global__ __launch_bounds__(256) void fused_kernel(const float* __restrict__ conf,
                                                    float* __restrict__ part) {
  __shared__ float4 P[NPOS];   // 16 KB
  __shared__ float wsx[4], wsy[4], wsz[4];
  __shared__ float red[4];

  const int g = blockIdx.x % NPG;
  const int b = blockIdx.x / NPG;
  const int tid = threadIdx.x;
  const int lane = tid & 63, w = tid >> 6;
  const float* __restrict__ row = conf + b * DROW;
  const float ALPHA = 2.40224481f;  // sqrt(5.770780163555856)

  // ---- phase 1: chain scan -> LDS positions ----
  float lx[4], ly[4], lz[4];
  float rx = 0.f, ry = 0.f, rz = 0.f;
#pragma unroll
  for (int k = 0; k < 4; ++k) {
    const int n = 4 * tid + k;
    if (n > 0) {
      const float2 rr = *reinterpret_cast<const float2*>(row + 2 + 2 * n);
      const float r1 = rr.x + 0.5f;
      const float r2 = rr.y + 0.5f;
      const float ct = 1.f - 2.f * r2;                    // cos(theta)
      const float st = sqrtf(fmaxf(0.f, 1.f - ct * ct));  // sin(theta)
      const float sp = __builtin_amdgcn_sinf(r1);         // sin(2*pi*r1)
      const float cp = __builtin_amdgcn_cosf(r1);
      rx += st * cp; ry += st * sp; rz += ct;
    }
    lx[k] = rx; ly[k] = ry; lz[k] = rz;
  }
  const float ttx = rx, tty = ry, ttz = rz;
  float sx = rx, sy = ry, sz = rz;
#pragma unroll
  for (int off = 1; off < 64; off <<= 1) {
    const float ax = __shfl_up(sx, off, 64);
    const float ay = __shfl_up(sy, off, 64);
    const float az = __shfl_up(sz, off, 64);
    if (lane >= off) { sx += ax; sy += ay; sz += az; }
  }
  if (lane == 63) { wsx[w] = sx; wsy[w] = sy; wsz[w] = sz; }
  __syncthreads();
  float cx = 0.f, cy = 0.f, cz = 0.f;
#pragma unroll
  for (int ww = 0; ww < 3; ++ww)
    if (ww < w) { cx += wsx[ww]; cy += wsy[ww]; cz += wsz[ww]; }

  const float ox = row[1] + cx + (sx - ttx);  // init + exclusive prefix
  const float oy = row[2] + cy + (sy - tty);
  const float oz = row[3] + cz + (sz - ttz);
#pragma unroll
  for (int k = 0; k < 4; ++k) {
    const float X = ALPHA * (ox + lx[k]);
    const float Y = ALPHA * (oy + ly[k]);
    const float Z = ALPHA * (oz + lz[k]);
    float n2 = X * X; n2 = fmaf(Y, Y, n2); n2 = fmaf(Z, Z, n2);
    P[4 * tid + k] = make_float4(X, Y, Z, -n2);
  }
  __syncthreads();

  // ---- phase 2: two triangular chunk-pairs, R=2 x j-quarter ----
  const int il = tid & 63;   // i lane within chunk (covers il and il+64)
  const int jq = w;          // wave id = j-quarter (wave-uniform)
  float total = 0.f;
#pragma unroll
  for (int s = 0; s < 2; ++s) {
    const int p = 2 * g + s;
    int ci, cj;
    float wgt;
    if (p < 8) {
      ci = p; cj = p; wgt = 1.f;
    } else {
      int r = p - 8;
      ci = 0;
      while (r >= 7 - ci) { r -= 7 - ci; ++ci; }
      cj = ci + 1 + r; wgt = 2.f;
    }
    const float4 A = P[ci * 128 + il];
    const float4 B = P[ci * 128 + il + 64];
    const float dAx = 2.f * A.x, dAy = 2.f * A.y, dAz = 2.f * A.z;
    const float dBx = 2.f * B.x, dBy = 2.f * B.y, dBz = 2.f * B.z;
    const float4* __restrict__ Q = &P[cj * 128 + jq * 32];
    float a0 = 0.f, a1 = 0.f;
#pragma unroll 4
    for (int jj = 0; jj < 32; ++jj) {
      const float4 q = Q[jj];  // wave-uniform -> broadcast
      const float gA = fmaf(dAx, q.x, fmaf(dAy, q.y, fmaf(dAz, q.z, A.w + q.w)));
      const float gB = fmaf(dBx, q.x, fmaf(dBy, q.y, fmaf(dBz, q.z, B.w + q.w)));
      a0 += __builtin_amdgcn_exp2f(gA);
      a1 += __builtin_amdgcn_exp2f(gB);
    }
    total = fmaf(wgt, a0 + a1, total);
  }

  // ---- block reduce -> part[bx] (non-atomic) ----
#pragma unroll
  for (int off = 32; off; off >>= 1) total += __shfl_down(total, off, 64);
  if (lane == 0) red[w] = total;
  __syncthreads();
  if (tid == 0) part[blockIdx.x] = (red[0] + red[1]) + (red[2] + red[3]);
}

__global__ __launch_bounds__(256) void reduce_kernel(const float* __restrict__ part,
                                                     float* __restrict__ out) {
  float s = 0.f;
  for (int i = threadIdx.x; i < NBLK; i += 256) s += part[i];
#pragma unroll
  for (int off = 32; off; off >>= 1) s += __shfl_down(s, off, 64);
  __shared__ float red[4];
  const int lane = threadIdx.x & 63, w = threadIdx.x >> 6;
  if (lane == 0) red[w] = s;
  __syncthreads();
  if (threadIdx.x == 0) {
    // SIGMA * sum - SIGMA * NPOS * NBATCH (i==j diagonal of diag chunks)
    out[0] = 10.0f * ((red[0] + red[1]) + (red[2] + red[3])) - 655360.0f;
  }
}

extern "C" void kernel_launch(void* const* d_in, const int* in_sizes, int n_in,
                              void* d_out, int out_size, void* d_ws, size_t ws_size,
                              hipStream_t stream) {
  const float* conf = (const float*)d_in[0];
  float* out = (float*)d_out;
  float* part = (float*)d_ws;  // NBLK floats
  hipLaunchKernelGGL(fused_kernel, dim3(NBLK), dim3(256), 0, stream, conf, part);
  hipLaunchKernelGGL(reduce_kernel, dim3(1), dim3(256), 0, stream, part, out);
}